// Round 1
// baseline (848.864 us; speedup 1.0000x reference)
//
#include <hip/hip_runtime.h>
#include <hip/hip_bf16.h>

// Problem constants (fixed by setup_inputs()):
constexpr int N = 10000;   // nodes
constexpr int D = 512;     // feature dim
constexpr int E = 160000;  // edges
constexpr int L = 3;       // layers
constexpr float EPS = 1e-5f;

// ---------------------------------------------------------------------------
// Degree counting: out_deg from src, in_deg from dst
// ---------------------------------------------------------------------------
__global__ void compute_degrees(const int* __restrict__ src,
                                const int* __restrict__ dst,
                                int* __restrict__ out_deg,
                                int* __restrict__ in_deg) {
    int e = blockIdx.x * blockDim.x + threadIdx.x;
    if (e >= E) return;
    atomicAdd(&out_deg[src[e]], 1);
    atomicAdd(&in_deg[dst[e]], 1);
}

// norms: deg^-1/2 with clip(deg,1)
__global__ void compute_norms(const int* __restrict__ out_deg,
                              const int* __restrict__ in_deg,
                              float* __restrict__ src_norm,
                              float* __restrict__ dst_norm) {
    int n = blockIdx.x * blockDim.x + threadIdx.x;
    if (n >= N) return;
    int od = out_deg[n]; if (od < 1) od = 1;
    int id = in_deg[n];  if (id < 1) id = 1;
    src_norm[n] = rsqrtf((float)od);
    dst_norm[n] = rsqrtf((float)id);
}

// ---------------------------------------------------------------------------
// Exclusive prefix sum of in_deg -> csr_off[N+1]. Single block, 1024 threads.
// ---------------------------------------------------------------------------
__global__ void scan_indeg(const int* __restrict__ deg, int* __restrict__ off) {
    __shared__ int lsum[1024];
    int t = threadIdx.x;
    const int chunk = (N + 1023) / 1024;
    int start = t * chunk;
    int end = start + chunk; if (end > N) end = N;
    int s = 0;
    for (int i = start; i < end; ++i) s += deg[i];
    lsum[t] = s;
    __syncthreads();
    // Hillis-Steele inclusive scan over 1024 chunk sums
    for (int d = 1; d < 1024; d <<= 1) {
        int v = (t >= d) ? lsum[t - d] : 0;
        __syncthreads();
        lsum[t] += v;
        __syncthreads();
    }
    int excl = (t == 0) ? 0 : lsum[t - 1];
    for (int i = start; i < end; ++i) {
        off[i] = excl;
        excl += deg[i];
    }
    if (t == 1023) off[N] = lsum[1023];
}

__global__ void copy_cursor(const int* __restrict__ off, int* __restrict__ cursor) {
    int n = blockIdx.x * blockDim.x + threadIdx.x;
    if (n < N) cursor[n] = off[n];
}

__global__ void csr_fill(const int* __restrict__ src, const int* __restrict__ dst,
                         int* __restrict__ cursor, int* __restrict__ csr_src) {
    int e = blockIdx.x * blockDim.x + threadIdx.x;
    if (e >= E) return;
    int d = dst[e];
    int pos = atomicAdd(&cursor[d], 1);
    csr_src[pos] = src[e];
}

// ---------------------------------------------------------------------------
// Column stats: stats[0..D) = sum, stats[D..2D) = sum of squares
// ---------------------------------------------------------------------------
__global__ void col_stats(const float* __restrict__ x, float* __restrict__ stats,
                          int rows_per_block) {
    int c = threadIdx.x;  // D == 512 threads
    int r0 = blockIdx.x * rows_per_block;
    int r1 = r0 + rows_per_block; if (r1 > N) r1 = N;
    float s = 0.f, ss = 0.f;
    for (int r = r0; r < r1; ++r) {
        float v = x[(size_t)r * D + c];
        s += v;
        ss += v * v;
    }
    atomicAdd(&stats[c], s);
    atomicAdd(&stats[D + c], ss);
}

// BN apply + multiply by src_norm -> h
__global__ void bn_apply(const float* __restrict__ x, const float* __restrict__ stats,
                         const float* __restrict__ gamma, const float* __restrict__ beta,
                         const float* __restrict__ src_norm, float* __restrict__ h) {
    int idx = blockIdx.x * blockDim.x + threadIdx.x;
    if (idx >= N * D) return;
    int c = idx & (D - 1);
    int n = idx >> 9;  // D == 512
    const float invN = 1.0f / (float)N;
    float mu = stats[c] * invN;
    float var = stats[D + c] * invN - mu * mu;
    float v = (x[idx] - mu) * rsqrtf(var + EPS) * gamma[c] + beta[c];
    h[idx] = v * src_norm[n];
}

// ---------------------------------------------------------------------------
// Aggregate: out[n,:] = dst_norm[n] * sum_{e in CSR[n]} h[csr_src[e], :]
// One block (512 threads) per dst node.
// ---------------------------------------------------------------------------
__global__ void aggregate(const float* __restrict__ h, const int* __restrict__ off,
                          const int* __restrict__ csr_src,
                          const float* __restrict__ dst_norm, float* __restrict__ out) {
    int n = blockIdx.x;
    int c = threadIdx.x;  // D == 512
    int e0 = off[n], e1 = off[n + 1];
    float acc = 0.f;
    for (int e = e0; e < e1; ++e) {
        int s = csr_src[e];
        acc += h[(size_t)s * D + c];
    }
    out[(size_t)n * D + c] = acc * dst_norm[n];
}

// ---------------------------------------------------------------------------
// C = relu(A @ W + bias). A: N x D, W: D x D row-major, C: N x D.
// 64x64 tile per 256-thread block, 4x4 per thread, BK=16.
// ---------------------------------------------------------------------------
__global__ __launch_bounds__(256) void matmul_bias_relu(
    const float* __restrict__ A, const float* __restrict__ W,
    const float* __restrict__ bias, float* __restrict__ C) {
    __shared__ float As[16][65];  // [k][m]
    __shared__ float Ws[16][65];  // [k][n]
    int tid = threadIdx.x;
    int row0 = blockIdx.y * 64;
    int col0 = blockIdx.x * 64;
    int tx = tid & 15;   // n-group
    int ty = tid >> 4;   // m-group
    float acc[4][4] = {};
    for (int k0 = 0; k0 < D; k0 += 16) {
        // load A tile: 64 rows x 16 k
        {
            int k = tid & 15;
            int mr = tid >> 4;
            for (int p = 0; p < 4; ++p) {
                int m = mr + p * 16;
                int gr = row0 + m;
                float v = (gr < N) ? A[(size_t)gr * D + k0 + k] : 0.f;
                As[k][m] = v;
            }
        }
        // load W tile: 16 k x 64 cols
        {
            int n = tid & 63;
            int kr = tid >> 6;
            for (int p = 0; p < 4; ++p) {
                int k = kr + p * 4;
                Ws[k][n] = W[(size_t)(k0 + k) * D + col0 + n];
            }
        }
        __syncthreads();
        for (int k = 0; k < 16; ++k) {
            float a[4], w[4];
            for (int i = 0; i < 4; ++i) a[i] = As[k][ty * 4 + i];
            for (int j = 0; j < 4; ++j) w[j] = Ws[k][tx * 4 + j];
            for (int i = 0; i < 4; ++i)
                for (int j = 0; j < 4; ++j)
                    acc[i][j] += a[i] * w[j];
        }
        __syncthreads();
    }
    for (int i = 0; i < 4; ++i) {
        int gr = row0 + ty * 4 + i;
        if (gr >= N) continue;
        for (int j = 0; j < 4; ++j) {
            int gc = col0 + tx * 4 + j;
            float v = acc[i][j] + bias[gc];
            C[(size_t)gr * D + gc] = fmaxf(v, 0.f);
        }
    }
}

// ---------------------------------------------------------------------------
extern "C" void kernel_launch(void* const* d_in, const int* in_sizes, int n_in,
                              void* d_out, int out_size, void* d_ws, size_t ws_size,
                              hipStream_t stream) {
    const float* x_in   = (const float*)d_in[0];
    const int*   src    = (const int*)d_in[1];
    const int*   dst    = (const int*)d_in[2];
    const float* gamma  = (const float*)d_in[3];
    const float* beta   = (const float*)d_in[4];
    const float* W      = (const float*)d_in[5];
    const float* b      = (const float*)d_in[6];
    float* out = (float*)d_out;

    // workspace carve-up
    float* bufA     = (float*)d_ws;           // N*D
    float* bufB     = bufA + (size_t)N * D;   // N*D
    float* src_norm = bufB + (size_t)N * D;   // N
    float* dst_norm = src_norm + N;           // N
    int*   out_deg  = (int*)(dst_norm + N);   // N
    int*   in_deg   = out_deg + N;            // N
    int*   csr_off  = in_deg + N;             // N+1
    int*   cursor   = csr_off + N + 1;        // N
    int*   csr_src  = cursor + N;             // E
    float* stats    = (float*)(csr_src + E);  // 2*D

    // --- graph structure (once per call) ---
    hipMemsetAsync(out_deg, 0, 2 * (size_t)N * sizeof(int), stream);
    compute_degrees<<<(E + 255) / 256, 256, 0, stream>>>(src, dst, out_deg, in_deg);
    compute_norms<<<(N + 255) / 256, 256, 0, stream>>>(out_deg, in_deg, src_norm, dst_norm);
    scan_indeg<<<1, 1024, 0, stream>>>(in_deg, csr_off);
    copy_cursor<<<(N + 255) / 256, 256, 0, stream>>>(csr_off, cursor);
    csr_fill<<<(E + 255) / 256, 256, 0, stream>>>(src, dst, cursor, csr_src);

    // --- layers ---
    // ping-pong: layer0: x=x_in, h=bufA, agg=bufB, out=bufA
    //            layer1: x=bufA, h=bufB, agg=bufA, out=bufB
    //            layer2: x=bufB, h=bufA, agg=bufB, out=d_out
    const float* x_ptr = x_in;
    float* h_ptr   = bufA;
    float* agg_ptr = bufB;
    float* o_ptr   = bufA;

    const int ew_blocks = (N * D + 255) / 256;
    dim3 mm_grid(D / 64, (N + 63) / 64);

    for (int l = 0; l < L; ++l) {
        hipMemsetAsync(stats, 0, 2 * D * sizeof(float), stream);
        col_stats<<<100, D, 0, stream>>>(x_ptr, stats, (N + 99) / 100);
        bn_apply<<<ew_blocks, 256, 0, stream>>>(x_ptr, stats, gamma + (size_t)l * D,
                                                beta + (size_t)l * D, src_norm, h_ptr);
        aggregate<<<N, D, 0, stream>>>(h_ptr, csr_off, csr_src, dst_norm, agg_ptr);
        float* mm_out = (l == L - 1) ? out : o_ptr;
        matmul_bias_relu<<<mm_grid, 256, 0, stream>>>(agg_ptr, W + (size_t)l * D * D,
                                                      b + (size_t)l * D, mm_out);
        // rotate buffers for next layer
        if (l == 0) { x_ptr = bufA; h_ptr = bufB; agg_ptr = bufA; o_ptr = bufB; }
        else        { x_ptr = bufB; h_ptr = bufA; agg_ptr = bufB; o_ptr = bufA; }
    }
}

// Round 2
// 445.465 us; speedup vs baseline: 1.9056x; 1.9056x over previous
//
#include <hip/hip_runtime.h>
#include <hip/hip_bf16.h>

constexpr int N = 10000;   // nodes
constexpr int D = 512;     // feature dim
constexpr int E = 160000;  // edges
constexpr int L = 3;       // layers
constexpr float EPS = 1e-5f;

typedef _Float16 half8 __attribute__((ext_vector_type(8)));
typedef _Float16 half4 __attribute__((ext_vector_type(4)));
typedef float floatx4 __attribute__((ext_vector_type(4)));

// ---------------------------------------------------------------------------
// Graph structure kernels
// ---------------------------------------------------------------------------
__global__ void compute_degrees(const int* __restrict__ src,
                                const int* __restrict__ dst,
                                int* __restrict__ out_deg,
                                int* __restrict__ in_deg) {
    int e = blockIdx.x * blockDim.x + threadIdx.x;
    if (e >= E) return;
    atomicAdd(&out_deg[src[e]], 1);
    atomicAdd(&in_deg[dst[e]], 1);
}

__global__ void compute_norms(const int* __restrict__ out_deg,
                              const int* __restrict__ in_deg,
                              float* __restrict__ src_norm,
                              float* __restrict__ dst_norm) {
    int n = blockIdx.x * blockDim.x + threadIdx.x;
    if (n >= N) return;
    int od = out_deg[n]; if (od < 1) od = 1;
    int id = in_deg[n];  if (id < 1) id = 1;
    src_norm[n] = rsqrtf((float)od);
    dst_norm[n] = rsqrtf((float)id);
}

__global__ void scan_indeg(const int* __restrict__ deg, int* __restrict__ off) {
    __shared__ int lsum[1024];
    int t = threadIdx.x;
    const int chunk = (N + 1023) / 1024;
    int start = t * chunk;
    int end = start + chunk; if (end > N) end = N;
    int s = 0;
    for (int i = start; i < end; ++i) s += deg[i];
    lsum[t] = s;
    __syncthreads();
    for (int d = 1; d < 1024; d <<= 1) {
        int v = (t >= d) ? lsum[t - d] : 0;
        __syncthreads();
        lsum[t] += v;
        __syncthreads();
    }
    int excl = (t == 0) ? 0 : lsum[t - 1];
    for (int i = start; i < end; ++i) {
        off[i] = excl;
        excl += deg[i];
    }
    if (t == 1023) off[N] = lsum[1023];
}

__global__ void copy_cursor(const int* __restrict__ off, int* __restrict__ cursor) {
    int n = blockIdx.x * blockDim.x + threadIdx.x;
    if (n < N) cursor[n] = off[n];
}

__global__ void csr_fill(const int* __restrict__ src, const int* __restrict__ dst,
                         int* __restrict__ cursor, int* __restrict__ csr_src) {
    int e = blockIdx.x * blockDim.x + threadIdx.x;
    if (e >= E) return;
    int d = dst[e];
    int pos = atomicAdd(&cursor[d], 1);
    csr_src[pos] = src[e];
}

// ---------------------------------------------------------------------------
// W conversion: Wt[l][n][k] = (f16) W[l][k][n]   (512x512 per layer)
// ---------------------------------------------------------------------------
__global__ void transpose_W(const float* __restrict__ W, _Float16* __restrict__ Wt) {
    __shared__ float t[32][33];
    int l = blockIdx.z;
    int k0 = blockIdx.x * 32, n0 = blockIdx.y * 32;
    int tx = threadIdx.x, ty = threadIdx.y;  // 32 x 8
    const float* Wl = W + (size_t)l * D * D;
    _Float16* Wtl = Wt + (size_t)l * D * D;
    for (int i = 0; i < 32; i += 8)
        t[ty + i][tx] = Wl[(size_t)(k0 + ty + i) * D + n0 + tx];
    __syncthreads();
    for (int i = 0; i < 32; i += 8)
        Wtl[(size_t)(n0 + ty + i) * D + k0 + tx] = (_Float16)t[tx][ty + i];
}

// ---------------------------------------------------------------------------
// Column stats (partials, no atomics): part[b*1024 + c] = sum, [.. + 512 + c] = sumsq
// ---------------------------------------------------------------------------
template <typename T>
__global__ void col_stats_part(const T* __restrict__ x, float* __restrict__ part,
                               int rows_per_block) {
    int c = threadIdx.x;  // 512
    int b = blockIdx.x;
    int r0 = b * rows_per_block;
    int r1 = r0 + rows_per_block; if (r1 > N) r1 = N;
    float s = 0.f, ss = 0.f;
    for (int r = r0; r < r1; ++r) {
        float v = (float)x[(size_t)r * D + c];
        s += v;
        ss += v * v;
    }
    part[b * 1024 + c] = s;
    part[b * 1024 + 512 + c] = ss;
}

// coef[c] = gamma*rsqrt(var+eps); coef[512+c] = beta - mu*scale
__global__ void bn_coef(const float* __restrict__ part, int nparts,
                        const float* __restrict__ gamma, const float* __restrict__ beta,
                        float* __restrict__ coef) {
    int c = threadIdx.x;  // 512
    float s = 0.f, ss = 0.f;
    for (int p = 0; p < nparts; ++p) {
        s += part[p * 1024 + c];
        ss += part[p * 1024 + 512 + c];
    }
    const float invN = 1.0f / (float)N;
    float mu = s * invN;
    float var = ss * invN - mu * mu;
    float scale = gamma[c] * rsqrtf(var + EPS);
    coef[c] = scale;
    coef[D + c] = beta[c] - mu * scale;
}

// h[n,c] = ((x - mu)*scale + shift) * src_norm[n], f16 out
template <typename T>
__global__ void bn_apply(const T* __restrict__ x, const float* __restrict__ coef,
                         const float* __restrict__ src_norm, _Float16* __restrict__ h) {
    int idx = blockIdx.x * 256 + threadIdx.x;  // group of 4 elements
    if (idx >= N * (D / 4)) return;
    int n = idx >> 7;           // D/4 == 128
    int c4 = (idx & 127) << 2;
    float sn = src_norm[n];
    half4 o;
    const T* xp = x + (size_t)n * D + c4;
    for (int i = 0; i < 4; ++i) {
        float v = (float)xp[i];
        o[i] = (_Float16)((v * coef[c4 + i] + coef[D + c4 + i]) * sn);
    }
    *(half4*)(h + (size_t)n * D + c4) = o;
}

// ---------------------------------------------------------------------------
// Aggregate: agg[n,:] = dst_norm[n] * sum_{e in CSR[n]} h[csr_src[e], :]
// 128 threads/block, 4 f16 per thread, fp32 accumulation.
// ---------------------------------------------------------------------------
__global__ void aggregate(const _Float16* __restrict__ h, const int* __restrict__ off,
                          const int* __restrict__ csr_src,
                          const float* __restrict__ dst_norm, _Float16* __restrict__ outA) {
    int n = blockIdx.x;
    int t = threadIdx.x;  // 0..127
    int e0 = off[n], e1 = off[n + 1];
    float a0 = 0.f, a1 = 0.f, a2 = 0.f, a3 = 0.f;
    for (int e = e0; e < e1; ++e) {
        int s = csr_src[e];
        half4 v = *(const half4*)(h + (size_t)s * D + t * 4);
        a0 += (float)v[0]; a1 += (float)v[1]; a2 += (float)v[2]; a3 += (float)v[3];
    }
    float dn = dst_norm[n];
    half4 o;
    o[0] = (_Float16)(a0 * dn); o[1] = (_Float16)(a1 * dn);
    o[2] = (_Float16)(a2 * dn); o[3] = (_Float16)(a3 * dn);
    *(half4*)(outA + (size_t)n * D + t * 4) = o;
}

// ---------------------------------------------------------------------------
// C = relu(A @ W + bias) via f16 MFMA.
// A: M x 512 f16 row-major.  Bt: 512 x 512 f16 with Bt[n][k] = W[k][n].
// OutT: _Float16 (intermediate x) or float (final output).
// Block: 256 threads = 4 waves; tile 128(M) x 128(N); BK = 32.
// Wave quadrants 64x64; per wave 4x4 tiles of mfma_f32_16x16x32_f16.
// ---------------------------------------------------------------------------
template <typename OutT>
__global__ __launch_bounds__(256) void mm_f16_relu(
    const _Float16* __restrict__ A, const _Float16* __restrict__ Bt,
    const float* __restrict__ bias, OutT* __restrict__ C, int M) {
    __shared__ __align__(16) _Float16 As[128 * 32];
    __shared__ __align__(16) _Float16 Bs[128 * 32];
    const int tid  = threadIdx.x;
    const int wave = tid >> 6;
    const int lane = tid & 63;
    const int quad = lane >> 4;
    const int l16  = lane & 15;
    const int row0 = blockIdx.x * 128;
    const int col0 = blockIdx.y * 128;
    const int wm = (wave & 1) * 64;
    const int wn = (wave >> 1) * 64;

    // staging slots: each thread covers 2 chunks of A and 2 of B (16 B each)
    const int sr = lane >> 2;        // row within a 16-row slab
    const int sc = (lane & 3) * 8;   // f16 offset within 32-wide k row

    floatx4 acc[4][4] = {};

    half8 pa[2], pb[2];
    // prefetch k0 = 0
    for (int p = 0; p < 2; ++p) {
        int ar = row0 + wave * 32 + p * 16 + sr;
        if (ar >= M) ar = M - 1;  // clamp (masked at store)
        pa[p] = *(const half8*)(A + (size_t)ar * D + sc);
        int br = col0 + wave * 32 + p * 16 + sr;
        pb[p] = *(const half8*)(Bt + (size_t)br * D + sc);
    }

    for (int k0 = 0; k0 < D; k0 += 32) {
        __syncthreads();  // previous compute done; LDS reusable
        for (int p = 0; p < 2; ++p) {
            int r = wave * 32 + p * 16 + sr;
            *(half8*)(As + r * 32 + sc) = pa[p];
            *(half8*)(Bs + r * 32 + sc) = pb[p];
        }
        __syncthreads();
        if (k0 + 32 < D) {
            int k1 = k0 + 32;
            for (int p = 0; p < 2; ++p) {
                int ar = row0 + wave * 32 + p * 16 + sr;
                if (ar >= M) ar = M - 1;
                pa[p] = *(const half8*)(A + (size_t)ar * D + k1 + sc);
                int br = col0 + wave * 32 + p * 16 + sr;
                pb[p] = *(const half8*)(Bt + (size_t)br * D + k1 + sc);
            }
        }
        half8 af[4], bf[4];
        for (int i = 0; i < 4; ++i)
            af[i] = *(const half8*)(As + (wm + i * 16 + l16) * 32 + quad * 8);
        for (int j = 0; j < 4; ++j)
            bf[j] = *(const half8*)(Bs + (wn + j * 16 + l16) * 32 + quad * 8);
        for (int i = 0; i < 4; ++i)
            for (int j = 0; j < 4; ++j)
                acc[i][j] = __builtin_amdgcn_mfma_f32_16x16x32_f16(af[i], bf[j], acc[i][j], 0, 0, 0);
    }

    // epilogue: C/D layout col = lane&15, row = quad*4 + reg
    for (int i = 0; i < 4; ++i) {
        for (int r = 0; r < 4; ++r) {
            int row = row0 + wm + i * 16 + quad * 4 + r;
            if (row >= M) continue;
            for (int j = 0; j < 4; ++j) {
                int col = col0 + wn + j * 16 + l16;
                float v = acc[i][j][r] + bias[col];
                C[(size_t)row * D + col] = (OutT)(v > 0.f ? v : 0.f);
            }
        }
    }
}

// ---------------------------------------------------------------------------
extern "C" void kernel_launch(void* const* d_in, const int* in_sizes, int n_in,
                              void* d_out, int out_size, void* d_ws, size_t ws_size,
                              hipStream_t stream) {
    const float* x_in  = (const float*)d_in[0];
    const int*   src   = (const int*)d_in[1];
    const int*   dst   = (const int*)d_in[2];
    const float* gamma = (const float*)d_in[3];
    const float* beta  = (const float*)d_in[4];
    const float* W     = (const float*)d_in[5];
    const float* b     = (const float*)d_in[6];
    float* out = (float*)d_out;

    // workspace carve-up (all 16B-aligned segments)
    char* p = (char*)d_ws;
    _Float16* xbuf = (_Float16*)p;        p += (size_t)N * D * 2;   // 10.24 MB
    _Float16* hbuf = (_Float16*)p;        p += (size_t)N * D * 2;   // 10.24 MB
    _Float16* agg  = (_Float16*)p;        p += (size_t)N * D * 2;   // 10.24 MB
    _Float16* Wt   = (_Float16*)p;        p += (size_t)L * D * D * 2;  // 1.57 MB
    float* part    = (float*)p;           p += 100 * 1024 * 4;      // 0.41 MB
    float* coef    = (float*)p;           p += 2 * D * 4;
    float* src_norm= (float*)p;           p += (size_t)N * 4;
    float* dst_norm= (float*)p;           p += (size_t)N * 4;
    int* out_deg   = (int*)p;             p += (size_t)N * 4;
    int* in_deg    = (int*)p;             p += (size_t)N * 4;
    int* csr_off   = (int*)p;             p += (size_t)(N + 1) * 4;
    int* cursor    = (int*)p;             p += (size_t)N * 4;
    int* csr_src   = (int*)p;             p += (size_t)E * 4;

    // --- graph structure + W conversion (once per call) ---
    hipMemsetAsync(out_deg, 0, 2 * (size_t)N * sizeof(int), stream);
    compute_degrees<<<(E + 255) / 256, 256, 0, stream>>>(src, dst, out_deg, in_deg);
    compute_norms<<<(N + 255) / 256, 256, 0, stream>>>(out_deg, in_deg, src_norm, dst_norm);
    scan_indeg<<<1, 1024, 0, stream>>>(in_deg, csr_off);
    copy_cursor<<<(N + 255) / 256, 256, 0, stream>>>(csr_off, cursor);
    csr_fill<<<(E + 255) / 256, 256, 0, stream>>>(src, dst, cursor, csr_src);
    transpose_W<<<dim3(16, 16, 3), dim3(32, 8), 0, stream>>>(W, Wt);

    const int bn_blocks = (N * (D / 4) + 255) / 256;
    dim3 mm_grid((N + 127) / 128, D / 128);

    for (int l = 0; l < L; ++l) {
        const float* gl = gamma + (size_t)l * D;
        const float* bl = beta + (size_t)l * D;
        const _Float16* Wl = Wt + (size_t)l * D * D;
        const float* bil = b + (size_t)l * D;

        if (l == 0) {
            col_stats_part<float><<<100, D, 0, stream>>>(x_in, part, (N + 99) / 100);
            bn_coef<<<1, D, 0, stream>>>(part, 100, gl, bl, coef);
            bn_apply<float><<<bn_blocks, 256, 0, stream>>>(x_in, coef, src_norm, hbuf);
        } else {
            col_stats_part<_Float16><<<100, D, 0, stream>>>(xbuf, part, (N + 99) / 100);
            bn_coef<<<1, D, 0, stream>>>(part, 100, gl, bl, coef);
            bn_apply<_Float16><<<bn_blocks, 256, 0, stream>>>(xbuf, coef, src_norm, hbuf);
        }
        aggregate<<<N, 128, 0, stream>>>(hbuf, csr_off, csr_src, dst_norm, agg);
        if (l == L - 1) {
            mm_f16_relu<float><<<mm_grid, 256, 0, stream>>>(agg, Wl, bil, out, N);
        } else {
            mm_f16_relu<_Float16><<<mm_grid, 256, 0, stream>>>(agg, Wl, bil, xbuf, N);
        }
    }
}

// Round 3
// 311.027 us; speedup vs baseline: 2.7292x; 1.4322x over previous
//
#include <hip/hip_runtime.h>
#include <hip/hip_bf16.h>

constexpr int N = 10000;   // nodes
constexpr int D = 512;     // feature dim
constexpr int E = 160000;  // edges
constexpr int L = 3;       // layers
constexpr float EPS = 1e-5f;

typedef _Float16 half8 __attribute__((ext_vector_type(8)));
typedef float floatx4 __attribute__((ext_vector_type(4)));

// ---------------------------------------------------------------------------
// Graph structure kernels
// ---------------------------------------------------------------------------
__global__ void compute_degrees(const int* __restrict__ src,
                                const int* __restrict__ dst,
                                int* __restrict__ out_deg,
                                int* __restrict__ in_deg) {
    int e = blockIdx.x * blockDim.x + threadIdx.x;
    if (e >= E) return;
    atomicAdd(&out_deg[src[e]], 1);
    atomicAdd(&in_deg[dst[e]], 1);
}

// Single block: exclusive scan of in_deg -> off & cursor, plus both norms.
__global__ void scan_indeg(const int* __restrict__ in_deg,
                           const int* __restrict__ out_deg,
                           int* __restrict__ off, int* __restrict__ cursor,
                           float* __restrict__ src_norm, float* __restrict__ dst_norm) {
    __shared__ int lsum[1024];
    int t = threadIdx.x;
    const int chunk = (N + 1023) / 1024;
    int start = t * chunk;
    int end = start + chunk; if (end > N) end = N;
    int s = 0;
    for (int i = start; i < end; ++i) s += in_deg[i];
    lsum[t] = s;
    __syncthreads();
    for (int d = 1; d < 1024; d <<= 1) {
        int v = (t >= d) ? lsum[t - d] : 0;
        __syncthreads();
        lsum[t] += v;
        __syncthreads();
    }
    int excl = (t == 0) ? 0 : lsum[t - 1];
    for (int i = start; i < end; ++i) {
        off[i] = excl;
        cursor[i] = excl;
        excl += in_deg[i];
        int od = out_deg[i]; if (od < 1) od = 1;
        int id = in_deg[i];  if (id < 1) id = 1;
        src_norm[i] = rsqrtf((float)od);
        dst_norm[i] = rsqrtf((float)id);
    }
    if (t == 1023) off[N] = lsum[1023];
}

__global__ void csr_fill(const int* __restrict__ src, const int* __restrict__ dst,
                         int* __restrict__ cursor, int* __restrict__ csr_src) {
    int e = blockIdx.x * blockDim.x + threadIdx.x;
    if (e >= E) return;
    int d = dst[e];
    int pos = atomicAdd(&cursor[d], 1);
    csr_src[pos] = src[e];
}

// ---------------------------------------------------------------------------
// W conversion: Wt[l][n][k] = (f16) W[l][k][n]
// ---------------------------------------------------------------------------
__global__ void transpose_W(const float* __restrict__ W, _Float16* __restrict__ Wt) {
    __shared__ float t[32][33];
    int l = blockIdx.z;
    int k0 = blockIdx.x * 32, n0 = blockIdx.y * 32;
    int tx = threadIdx.x, ty = threadIdx.y;  // 32 x 8
    const float* Wl = W + (size_t)l * D * D;
    _Float16* Wtl = Wt + (size_t)l * D * D;
    for (int i = 0; i < 32; i += 8)
        t[ty + i][tx] = Wl[(size_t)(k0 + ty + i) * D + n0 + tx];
    __syncthreads();
    for (int i = 0; i < 32; i += 8)
        Wtl[(size_t)(n0 + ty + i) * D + k0 + tx] = (_Float16)t[tx][ty + i];
}

// x_in fp32 -> f16
__global__ void convert_x(const float* __restrict__ x, _Float16* __restrict__ y) {
    int i = blockIdx.x * 256 + threadIdx.x;  // group of 8
    if (i >= N * D / 8) return;
    const float* xp = x + (size_t)i * 8;
    half8 o;
    for (int k = 0; k < 8; ++k) o[k] = (_Float16)xp[k];
    *(half8*)(y + (size_t)i * 8) = o;
}

// Column stats of x16 -> stats[c]=sum, stats[D+c]=sumsq (atomic accumulate)
__global__ void col_stats(const _Float16* __restrict__ x, float* __restrict__ stats,
                          int rows_per_block) {
    int c = threadIdx.x;  // 512
    int r0 = blockIdx.x * rows_per_block;
    int r1 = r0 + rows_per_block; if (r1 > N) r1 = N;
    float s = 0.f, ss = 0.f;
    for (int r = r0; r < r1; ++r) {
        float v = (float)x[(size_t)r * D + c];
        s += v;
        ss += v * v;
    }
    atomicAdd(&stats[c], s);
    atomicAdd(&stats[D + c], ss);
}

// coef from stats; zero stats for next layer's accumulation.
__global__ void bn_coef(float* __restrict__ stats,
                        const float* __restrict__ gamma, const float* __restrict__ beta,
                        float* __restrict__ coef) {
    int c = threadIdx.x;  // 512
    const float invN = 1.0f / (float)N;
    float mu = stats[c] * invN;
    float var = stats[D + c] * invN - mu * mu;
    float scale = gamma[c] * rsqrtf(var + EPS);
    coef[c] = scale;
    coef[D + c] = beta[c] - mu * scale;
    stats[c] = 0.f;
    stats[D + c] = 0.f;
}

// ---------------------------------------------------------------------------
// Fused BN + gather-aggregate. One wave per dst node.
// agg[n] = dst_norm[n] * (scale ⊙ Σ_e x[s]*sn[s]  +  shift * Σ_e sn[s])
// ---------------------------------------------------------------------------
__global__ __launch_bounds__(256) void aggregate_bn(
    const _Float16* __restrict__ x, const int* __restrict__ off,
    const int* __restrict__ csr_src, const float* __restrict__ src_norm,
    const float* __restrict__ dst_norm, const float* __restrict__ coef,
    _Float16* __restrict__ agg) {
    int wid = (blockIdx.x * 256 + threadIdx.x) >> 6;
    if (wid >= N) return;
    int lane = threadIdx.x & 63;
    int c0 = lane * 8;
    int e0 = off[wid], e1 = off[wid + 1];
    float a[8] = {}, a2[8] = {};
    float t = 0.f;
    int e = e0;
    for (; e + 2 <= e1; e += 2) {
        int s0 = csr_src[e];
        int s1 = csr_src[e + 1];
        float n0 = src_norm[s0];
        float n1 = src_norm[s1];
        half8 v0 = *(const half8*)(x + (size_t)s0 * D + c0);
        half8 v1 = *(const half8*)(x + (size_t)s1 * D + c0);
        t += n0 + n1;
        for (int i = 0; i < 8; ++i) {
            a[i]  += (float)v0[i] * n0;
            a2[i] += (float)v1[i] * n1;
        }
    }
    if (e < e1) {
        int s0 = csr_src[e];
        float n0 = src_norm[s0];
        half8 v0 = *(const half8*)(x + (size_t)s0 * D + c0);
        t += n0;
        for (int i = 0; i < 8; ++i) a[i] += (float)v0[i] * n0;
    }
    float dn = dst_norm[wid];
    half8 o;
    for (int i = 0; i < 8; ++i) {
        float sc = coef[c0 + i];
        float sh = coef[D + c0 + i];
        o[i] = (_Float16)(dn * (sc * (a[i] + a2[i]) + sh * t));
    }
    *(half8*)(agg + (size_t)wid * D + c0) = o;
}

// ---------------------------------------------------------------------------
// C = relu(A @ W + bias) via f16 MFMA, optional fused column-stats epilogue.
// A: M x 512 f16.  Bt[n][k] = W[k][n] f16.
// Block 256 = 4 waves; tile 128x128; BK=32; per-wave 64x64 via 4x4 mfma 16x16x32.
// ---------------------------------------------------------------------------
template <typename OutT, bool STATS>
__global__ __launch_bounds__(256) void mm_f16_relu(
    const _Float16* __restrict__ A, const _Float16* __restrict__ Bt,
    const float* __restrict__ bias, OutT* __restrict__ C, int M,
    float* __restrict__ stats) {
    __shared__ __align__(16) _Float16 As[128 * 32];
    __shared__ __align__(16) _Float16 Bs[128 * 32];
    const int tid  = threadIdx.x;
    const int wave = tid >> 6;
    const int lane = tid & 63;
    const int quad = lane >> 4;
    const int l16  = lane & 15;
    const int row0 = blockIdx.x * 128;
    const int col0 = blockIdx.y * 128;
    const int wm = (wave & 1) * 64;
    const int wn = (wave >> 1) * 64;

    const int sr = lane >> 2;
    const int sc = (lane & 3) * 8;

    floatx4 acc[4][4] = {};

    half8 pa[2], pb[2];
    for (int p = 0; p < 2; ++p) {
        int ar = row0 + wave * 32 + p * 16 + sr;
        if (ar >= M) ar = M - 1;
        pa[p] = *(const half8*)(A + (size_t)ar * D + sc);
        int br = col0 + wave * 32 + p * 16 + sr;
        pb[p] = *(const half8*)(Bt + (size_t)br * D + sc);
    }

    for (int k0 = 0; k0 < D; k0 += 32) {
        __syncthreads();
        for (int p = 0; p < 2; ++p) {
            int r = wave * 32 + p * 16 + sr;
            *(half8*)(As + r * 32 + sc) = pa[p];
            *(half8*)(Bs + r * 32 + sc) = pb[p];
        }
        __syncthreads();
        if (k0 + 32 < D) {
            int k1 = k0 + 32;
            for (int p = 0; p < 2; ++p) {
                int ar = row0 + wave * 32 + p * 16 + sr;
                if (ar >= M) ar = M - 1;
                pa[p] = *(const half8*)(A + (size_t)ar * D + k1 + sc);
                int br = col0 + wave * 32 + p * 16 + sr;
                pb[p] = *(const half8*)(Bt + (size_t)br * D + k1 + sc);
            }
        }
        half8 af[4], bf[4];
        for (int i = 0; i < 4; ++i)
            af[i] = *(const half8*)(As + (wm + i * 16 + l16) * 32 + quad * 8);
        for (int j = 0; j < 4; ++j)
            bf[j] = *(const half8*)(Bs + (wn + j * 16 + l16) * 32 + quad * 8);
        for (int i = 0; i < 4; ++i)
            for (int j = 0; j < 4; ++j)
                acc[i][j] = __builtin_amdgcn_mfma_f32_16x16x32_f16(af[i], bf[j], acc[i][j], 0, 0, 0);
    }

    // epilogue: C/D layout col = lane&15, row = quad*4 + reg
    float s[4] = {}, ss[4] = {};
    for (int i = 0; i < 4; ++i) {
        for (int r = 0; r < 4; ++r) {
            int row = row0 + wm + i * 16 + quad * 4 + r;
            bool valid = row < M;
            for (int j = 0; j < 4; ++j) {
                int col = col0 + wn + j * 16 + l16;
                float v = acc[i][j][r] + bias[col];
                v = v > 0.f ? v : 0.f;
                if (valid) {
                    C[(size_t)row * D + col] = (OutT)v;
                    if (STATS) { s[j] += v; ss[j] += v * v; }
                }
            }
        }
    }
    if (STATS) {
        for (int j = 0; j < 4; ++j) {
            float sv = s[j], qv = ss[j];
            sv += __shfl_xor(sv, 16); sv += __shfl_xor(sv, 32);
            qv += __shfl_xor(qv, 16); qv += __shfl_xor(qv, 32);
            if (quad == 0) {
                int col = col0 + wn + j * 16 + l16;
                atomicAdd(&stats[col], sv);
                atomicAdd(&stats[D + col], qv);
            }
        }
    }
}

// ---------------------------------------------------------------------------
extern "C" void kernel_launch(void* const* d_in, const int* in_sizes, int n_in,
                              void* d_out, int out_size, void* d_ws, size_t ws_size,
                              hipStream_t stream) {
    const float* x_in  = (const float*)d_in[0];
    const int*   src   = (const int*)d_in[1];
    const int*   dst   = (const int*)d_in[2];
    const float* gamma = (const float*)d_in[3];
    const float* beta  = (const float*)d_in[4];
    const float* W     = (const float*)d_in[5];
    const float* b     = (const float*)d_in[6];
    float* out = (float*)d_out;

    // workspace carve-up (16B-aligned segments first)
    char* p = (char*)d_ws;
    _Float16* x16 = (_Float16*)p;  p += (size_t)N * D * 2;       // 10.24 MB
    _Float16* agg = (_Float16*)p;  p += (size_t)N * D * 2;       // 10.24 MB
    _Float16* Wt  = (_Float16*)p;  p += (size_t)L * D * D * 2;   // 1.57 MB
    float* coef     = (float*)p;   p += 2 * D * 4;
    float* src_norm = (float*)p;   p += (size_t)N * 4;
    float* dst_norm = (float*)p;   p += (size_t)N * 4;
    // contiguous zero-init region: out_deg, in_deg, stats
    int* out_deg = (int*)p;        p += (size_t)N * 4;
    int* in_deg  = (int*)p;        p += (size_t)N * 4;
    float* stats = (float*)p;      p += 2 * D * 4;
    int* csr_off = (int*)p;        p += (size_t)(N + 1) * 4;
    int* cursor  = (int*)p;        p += (size_t)N * 4;
    int* csr_src = (int*)p;        p += (size_t)E * 4;

    // --- setup (once per call) ---
    hipMemsetAsync(out_deg, 0, (2 * (size_t)N + 2 * D) * sizeof(int), stream);
    compute_degrees<<<(E + 255) / 256, 256, 0, stream>>>(src, dst, out_deg, in_deg);
    scan_indeg<<<1, 1024, 0, stream>>>(in_deg, out_deg, csr_off, cursor, src_norm, dst_norm);
    csr_fill<<<(E + 255) / 256, 256, 0, stream>>>(src, dst, cursor, csr_src);
    transpose_W<<<dim3(16, 16, 3), dim3(32, 8), 0, stream>>>(W, Wt);
    convert_x<<<(N * D / 8 + 255) / 256, 256, 0, stream>>>(x_in, x16);
    col_stats<<<100, D, 0, stream>>>(x16, stats, (N + 99) / 100);

    dim3 mm_grid((N + 127) / 128, D / 128);
    const int agg_blocks = (N + 3) / 4;  // 4 waves per 256-thread block

    for (int l = 0; l < L; ++l) {
        const float* gl  = gamma + (size_t)l * D;
        const float* bl  = beta + (size_t)l * D;
        const _Float16* Wl = Wt + (size_t)l * D * D;
        const float* bil = b + (size_t)l * D;

        bn_coef<<<1, D, 0, stream>>>(stats, gl, bl, coef);
        aggregate_bn<<<agg_blocks, 256, 0, stream>>>(x16, csr_off, csr_src,
                                                     src_norm, dst_norm, coef, agg);
        if (l == L - 1) {
            mm_f16_relu<float, false><<<mm_grid, 256, 0, stream>>>(
                agg, Wl, bil, out, N, nullptr);
        } else {
            mm_f16_relu<_Float16, true><<<mm_grid, 256, 0, stream>>>(
                agg, Wl, bil, x16, N, stats);
        }
    }
}

// Round 4
// 282.514 us; speedup vs baseline: 3.0047x; 1.1009x over previous
//
#include <hip/hip_runtime.h>
#include <hip/hip_bf16.h>

constexpr int N = 10000;   // nodes
constexpr int D = 512;     // feature dim
constexpr int E = 160000;  // edges
constexpr int L = 3;       // layers
constexpr float EPS = 1e-5f;

typedef _Float16 half8 __attribute__((ext_vector_type(8)));
typedef _Float16 half2v __attribute__((ext_vector_type(2)));
typedef float floatx4 __attribute__((ext_vector_type(4)));

// async global->LDS, 16B per lane. LDS dest = wave-uniform base + lane*16.
__device__ __forceinline__ void glds16(const _Float16* g, _Float16* l) {
    __builtin_amdgcn_global_load_lds(
        (const __attribute__((address_space(1))) uint32_t*)(g),
        (__attribute__((address_space(3))) uint32_t*)(l),
        16, 0, 0);
}

// ---------------------------------------------------------------------------
// Mega setup: degrees + x fp32->f16 conversion + column stats + W transpose.
// Roles by blockIdx.x.
// ---------------------------------------------------------------------------
constexpr int DEG_BLOCKS  = (E + 255) / 256;   // 625
constexpr int CONV_BLOCKS = 100;               // 100 rows each
constexpr int TW_BLOCKS   = L * 256;           // 768 (32x32 tiles)
constexpr int MEGA_BLOCKS = DEG_BLOCKS + CONV_BLOCKS + TW_BLOCKS;

__global__ __launch_bounds__(256) void mega_setup(
    const int* __restrict__ src, const int* __restrict__ dst,
    const float* __restrict__ x, const float* __restrict__ W,
    int* __restrict__ out_deg, int* __restrict__ in_deg,
    _Float16* __restrict__ x16, float* __restrict__ stats0,
    _Float16* __restrict__ Wt) {
    __shared__ float tb[32][33];
    int bid = blockIdx.x;
    int tid = threadIdx.x;
    if (bid < DEG_BLOCKS) {
        int e = bid * 256 + tid;
        if (e < E) {
            atomicAdd(&out_deg[src[e]], 1);
            atomicAdd(&in_deg[dst[e]], 1);
        }
    } else if (bid < DEG_BLOCKS + CONV_BLOCKS) {
        int b = bid - DEG_BLOCKS;
        int r0 = b * 100;
        int r1 = r0 + 100; if (r1 > N) r1 = N;
        int c2 = tid * 2;
        float s0 = 0.f, s1 = 0.f, q0 = 0.f, q1 = 0.f;
        for (int r = r0; r < r1; ++r) {
            float2 v = *(const float2*)(x + (size_t)r * D + c2);
            s0 += v.x; q0 += v.x * v.x;
            s1 += v.y; q1 += v.y * v.y;
            half2v h; h[0] = (_Float16)v.x; h[1] = (_Float16)v.y;
            *(half2v*)(x16 + (size_t)r * D + c2) = h;
        }
        atomicAdd(&stats0[c2], s0);
        atomicAdd(&stats0[c2 + 1], s1);
        atomicAdd(&stats0[D + c2], q0);
        atomicAdd(&stats0[D + c2 + 1], q1);
    } else {
        int b = bid - DEG_BLOCKS - CONV_BLOCKS;  // 0..767
        int l = b >> 8;
        int t = b & 255;
        int k0 = (t >> 4) * 32, n0 = (t & 15) * 32;
        int tx = tid & 31, ty = tid >> 5;  // 32 x 8
        const float* Wl = W + (size_t)l * D * D;
        _Float16* Wtl = Wt + (size_t)l * D * D;
        for (int i = 0; i < 32; i += 8)
            tb[ty + i][tx] = Wl[(size_t)(k0 + ty + i) * D + n0 + tx];
        __syncthreads();
        for (int i = 0; i < 32; i += 8)
            Wtl[(size_t)(n0 + ty + i) * D + k0 + tx] = (_Float16)tb[tx][ty + i];
    }
}

// ---------------------------------------------------------------------------
// Single block: exclusive scan of in_deg -> off & cursor, plus both norms.
// ---------------------------------------------------------------------------
__global__ void scan_indeg(const int* __restrict__ in_deg,
                           const int* __restrict__ out_deg,
                           int* __restrict__ off, int* __restrict__ cursor,
                           float* __restrict__ src_norm, float* __restrict__ dst_norm) {
    __shared__ int lsum[1024];
    int t = threadIdx.x;
    const int chunk = (N + 1023) / 1024;
    int start = t * chunk;
    int end = start + chunk; if (end > N) end = N;
    int s = 0;
    for (int i = start; i < end; ++i) s += in_deg[i];
    lsum[t] = s;
    __syncthreads();
    for (int d = 1; d < 1024; d <<= 1) {
        int v = (t >= d) ? lsum[t - d] : 0;
        __syncthreads();
        lsum[t] += v;
        __syncthreads();
    }
    int excl = (t == 0) ? 0 : lsum[t - 1];
    for (int i = start; i < end; ++i) {
        off[i] = excl;
        cursor[i] = excl;
        excl += in_deg[i];
        int od = out_deg[i]; if (od < 1) od = 1;
        int id = in_deg[i];  if (id < 1) id = 1;
        src_norm[i] = rsqrtf((float)od);
        dst_norm[i] = rsqrtf((float)id);
    }
    if (t == 1023) off[N] = lsum[1023];
}

__global__ void csr_fill(const int* __restrict__ src, const int* __restrict__ dst,
                         int* __restrict__ cursor, int* __restrict__ csr_src) {
    int e = blockIdx.x * blockDim.x + threadIdx.x;
    if (e >= E) return;
    int d = dst[e];
    int pos = atomicAdd(&cursor[d], 1);
    csr_src[pos] = src[e];
}

// ---------------------------------------------------------------------------
// Fused BN + gather-aggregate, coef computed in-register from stats.
// One wave per dst node.
// agg[n] = dst_norm[n] * (scale ⊙ Σ_e x[s]*sn[s]  +  shift * Σ_e sn[s])
// ---------------------------------------------------------------------------
__global__ __launch_bounds__(256) void aggregate_bn(
    const _Float16* __restrict__ x, const int* __restrict__ off,
    const int* __restrict__ csr_src, const float* __restrict__ src_norm,
    const float* __restrict__ dst_norm, const float* __restrict__ stats,
    const float* __restrict__ gamma, const float* __restrict__ beta,
    _Float16* __restrict__ agg) {
    int wid = (blockIdx.x * 256 + threadIdx.x) >> 6;
    if (wid >= N) return;
    int lane = threadIdx.x & 63;
    int c0 = lane * 8;

    float scale[8], shift[8];
    const float invN = 1.0f / (float)N;
    for (int i = 0; i < 8; ++i) {
        int c = c0 + i;
        float mu = stats[c] * invN;
        float var = stats[D + c] * invN - mu * mu;
        float sc = gamma[c] * rsqrtf(var + EPS);
        scale[i] = sc;
        shift[i] = beta[c] - mu * sc;
    }

    int e0 = off[wid], e1 = off[wid + 1];
    float a[8] = {}, a2[8] = {};
    float t = 0.f;
    int e = e0;
    for (; e + 2 <= e1; e += 2) {
        int s0 = csr_src[e];
        int s1 = csr_src[e + 1];
        float n0 = src_norm[s0];
        float n1 = src_norm[s1];
        half8 v0 = *(const half8*)(x + (size_t)s0 * D + c0);
        half8 v1 = *(const half8*)(x + (size_t)s1 * D + c0);
        t += n0 + n1;
        for (int i = 0; i < 8; ++i) {
            a[i]  += (float)v0[i] * n0;
            a2[i] += (float)v1[i] * n1;
        }
    }
    if (e < e1) {
        int s0 = csr_src[e];
        float n0 = src_norm[s0];
        half8 v0 = *(const half8*)(x + (size_t)s0 * D + c0);
        t += n0;
        for (int i = 0; i < 8; ++i) a[i] += (float)v0[i] * n0;
    }
    float dn = dst_norm[wid];
    half8 o;
    for (int i = 0; i < 8; ++i)
        o[i] = (_Float16)(dn * (scale[i] * (a[i] + a2[i]) + shift[i] * t));
    *(half8*)(agg + (size_t)wid * D + c0) = o;
}

// ---------------------------------------------------------------------------
// C = relu(A @ W + bias) via f16 MFMA with global_load_lds staging.
// A: M x 512 f16.  Bt[n][k] = W[k][n] f16.
// Block 256 = 4 waves; tile 128(M) x 64(N); BK=32.
// Wave computes 64x32 (4x2 tiles of mfma_f32_16x16x32_f16).
// ---------------------------------------------------------------------------
template <typename OutT, bool STATS>
__global__ __launch_bounds__(256) void mm_f16_relu(
    const _Float16* __restrict__ A, const _Float16* __restrict__ Bt,
    const float* __restrict__ bias, OutT* __restrict__ C, int M,
    float* __restrict__ stats) {
    __shared__ __align__(16) _Float16 As[128 * 32];
    __shared__ __align__(16) _Float16 Bs[64 * 32];
    const int tid  = threadIdx.x;
    const int wave = tid >> 6;
    const int lane = tid & 63;
    const int quad = lane >> 4;
    const int l16  = lane & 15;
    const int row0 = blockIdx.x * 128;
    const int col0 = blockIdx.y * 64;
    const int wm = (wave & 1) * 64;
    const int wn = (wave >> 1) * 32;
    const int sr = lane >> 2;
    const int sc = (lane & 3) * 8;

    // staging: wave w loads A rows [w*32, w*32+32) (two 16-row slabs)
    // and B rows [w*16, w*16+16). Per-lane global ptr, wave-uniform LDS base.
    int ar0 = row0 + wave * 32 + sr;
    int ar1 = ar0 + 16;
    if (ar0 >= M) ar0 = M - 1;
    if (ar1 >= M) ar1 = M - 1;
    const _Float16* gA0 = A + (size_t)ar0 * D + sc;
    const _Float16* gA1 = A + (size_t)ar1 * D + sc;
    const _Float16* gB  = Bt + (size_t)(col0 + wave * 16 + sr) * D + sc;
    _Float16* lA0 = As + (wave * 32) * 32;
    _Float16* lA1 = As + (wave * 32 + 16) * 32;
    _Float16* lB  = Bs + (wave * 16) * 32;

    floatx4 acc[4][2] = {};

    for (int k0 = 0; k0 < D; k0 += 32) {
        __syncthreads();
        glds16(gA0 + k0, lA0);
        glds16(gA1 + k0, lA1);
        glds16(gB + k0, lB);
        __syncthreads();  // compiler inserts vmcnt(0) drain here
        half8 af[4], bf[2];
        for (int i = 0; i < 4; ++i)
            af[i] = *(const half8*)(As + (wm + i * 16 + l16) * 32 + quad * 8);
        for (int j = 0; j < 2; ++j)
            bf[j] = *(const half8*)(Bs + (wn + j * 16 + l16) * 32 + quad * 8);
        for (int i = 0; i < 4; ++i)
            for (int j = 0; j < 2; ++j)
                acc[i][j] = __builtin_amdgcn_mfma_f32_16x16x32_f16(af[i], bf[j], acc[i][j], 0, 0, 0);
    }

    // epilogue: C/D layout col = lane&15, row = quad*4 + reg
    float s[2] = {}, q[2] = {};
    for (int i = 0; i < 4; ++i) {
        for (int r = 0; r < 4; ++r) {
            int row = row0 + wm + i * 16 + quad * 4 + r;
            bool valid = row < M;
            for (int j = 0; j < 2; ++j) {
                int col = col0 + wn + j * 16 + l16;
                float v = acc[i][j][r] + bias[col];
                v = v > 0.f ? v : 0.f;
                if (valid) {
                    C[(size_t)row * D + col] = (OutT)v;
                    if (STATS) { s[j] += v; q[j] += v * v; }
                }
            }
        }
    }
    if (STATS) {
        for (int j = 0; j < 2; ++j) {
            float sv = s[j], qv = q[j];
            sv += __shfl_xor(sv, 16); sv += __shfl_xor(sv, 32);
            qv += __shfl_xor(qv, 16); qv += __shfl_xor(qv, 32);
            if (quad == 0) {
                int col = col0 + wn + j * 16 + l16;
                atomicAdd(&stats[col], sv);
                atomicAdd(&stats[D + col], qv);
            }
        }
    }
}

// ---------------------------------------------------------------------------
extern "C" void kernel_launch(void* const* d_in, const int* in_sizes, int n_in,
                              void* d_out, int out_size, void* d_ws, size_t ws_size,
                              hipStream_t stream) {
    const float* x_in  = (const float*)d_in[0];
    const int*   src   = (const int*)d_in[1];
    const int*   dst   = (const int*)d_in[2];
    const float* gamma = (const float*)d_in[3];
    const float* beta  = (const float*)d_in[4];
    const float* W     = (const float*)d_in[5];
    const float* b     = (const float*)d_in[6];
    float* out = (float*)d_out;

    // workspace carve-up (16B-aligned segments first)
    char* p = (char*)d_ws;
    _Float16* x16 = (_Float16*)p;  p += (size_t)N * D * 2;       // 10.24 MB
    _Float16* agg = (_Float16*)p;  p += (size_t)N * D * 2;       // 10.24 MB
    _Float16* Wt  = (_Float16*)p;  p += (size_t)L * D * D * 2;   // 1.57 MB
    float* src_norm = (float*)p;   p += (size_t)N * 4;
    float* dst_norm = (float*)p;   p += (size_t)N * 4;
    // contiguous zero-init region: out_deg, in_deg, stats0..2
    int* out_deg   = (int*)p;      p += (size_t)N * 4;
    int* in_deg    = (int*)p;      p += (size_t)N * 4;
    float* stats0  = (float*)p;    p += 2 * D * 4;
    float* stats1  = (float*)p;    p += 2 * D * 4;
    float* stats2  = (float*)p;    p += 2 * D * 4;
    int* csr_off   = (int*)p;      p += (size_t)(N + 1) * 4;
    int* cursor    = (int*)p;      p += (size_t)N * 4;
    int* csr_src   = (int*)p;      p += (size_t)E * 4;

    float* stats_in[3] = {stats0, stats1, stats2};

    // --- setup ---
    hipMemsetAsync(out_deg, 0, (2 * (size_t)N + 6 * D) * sizeof(int), stream);
    mega_setup<<<MEGA_BLOCKS, 256, 0, stream>>>(src, dst, x_in, W,
                                                out_deg, in_deg, x16, stats0, Wt);
    scan_indeg<<<1, 1024, 0, stream>>>(in_deg, out_deg, csr_off, cursor,
                                       src_norm, dst_norm);
    csr_fill<<<DEG_BLOCKS, 256, 0, stream>>>(src, dst, cursor, csr_src);

    dim3 mm_grid((N + 127) / 128, D / 64);
    const int agg_blocks = (N + 3) / 4;  // 4 waves per 256-thread block

    for (int l = 0; l < L; ++l) {
        const float* gl  = gamma + (size_t)l * D;
        const float* bl  = beta + (size_t)l * D;
        const _Float16* Wl = Wt + (size_t)l * D * D;
        const float* bil = b + (size_t)l * D;

        aggregate_bn<<<agg_blocks, 256, 0, stream>>>(
            x16, csr_off, csr_src, src_norm, dst_norm, stats_in[l], gl, bl, agg);
        if (l == L - 1) {
            mm_f16_relu<float, false><<<mm_grid, 256, 0, stream>>>(
                agg, Wl, bil, out, N, nullptr);
        } else {
            mm_f16_relu<_Float16, true><<<mm_grid, 256, 0, stream>>>(
                agg, Wl, bil, x16, N, stats_in[l + 1]);
        }
    }
}